// Round 14
// baseline (59.289 us; speedup 1.0000x reference)
//
#include <hip/hip_runtime.h>

#define B_    1024
#define NIN_  126
#define NOUT_ 126
#define K_    3
#define H1_   256
#define H2_   256
#define RPB   4
#define TPB   512    // 8 waves, 1 block/CU, grid = 256
#define REPS  6      // internal repeat: surfaces real-kernel counters in top-5

__device__ __forceinline__ float elu1(float v) { return v > 0.0f ? v : expm1f(v); }

template<int CTRL>
__device__ __forceinline__ float dpp_add(float v) {
    int s = __builtin_amdgcn_update_dpp(0, __float_as_int(v), CTRL, 0xF, 0xF, true);
    return v + __int_as_float(s);
}
__device__ __forceinline__ float qsum8(float v) {
    v = dpp_add<0xB1>(v);
    v = dpp_add<0x4E>(v);
    int s = __builtin_amdgcn_ds_swizzle(__float_as_int(v), 0x101F);
    return v + __int_as_float(s);
}
__device__ __forceinline__ void barrier_lds() {
    asm volatile("s_waitcnt lgkmcnt(0)\n\ts_barrier" ::: "memory");
}
// runtime zero the compiler cannot see through (prevents cross-iteration hoisting)
__device__ __forceinline__ int opaque_zero() {
    int z;
    asm volatile("v_mov_b32 %0, 0" : "=v"(z));
    return z;
}

__global__ __launch_bounds__(TPB) void bim_fused(
    const float* __restrict__ x_,  const float* __restrict__ W0_,
    const float* __restrict__ b0_, const float* __restrict__ W1_,
    const float* __restrict__ b1_, const float* __restrict__ W2_,
    const float* __restrict__ b2_, const int*  __restrict__ iidx_,
    const int*  __restrict__ oidx_, float* __restrict__ out)
{
    __shared__ float xe [RPB][128];
    __shared__ float h1s[RPB][H1_];
    __shared__ float h2s[RPB][H2_];
    __shared__ float ts [RPB][128];

    const int tid  = threadIdx.x;
    const int row0 = blockIdx.x * RPB;
    const int q    = tid & 7;
    const int g    = tid >> 3;

    #pragma unroll 1
    for (int rep = 0; rep < REPS; ++rep) {
        const int z = opaque_zero();                 // defeats load hoisting
        const float* x   = x_   + z;
        const float* W0  = W0_  + z;
        const float* b0  = b0_  + z;
        const float* W1  = W1_  + z;
        const float* b1  = b1_  + z;
        const float* W2  = W2_  + z;
        const float* b2  = b2_  + z;
        const int*  iidx = iidx_ + z;
        const int*  oidx = oidx_ + z;

        // ---- phase-A operands ----
        int aj0, aj1, aj2, ar0, ar1, ar2; float ax0, ax1, ax2;
        {
            const int n0 = tid;
            ar0 = n0 / (NIN_ * K_); const int m0 = n0 - ar0 * (NIN_ * K_);
            aj0 = iidx[(row0 + ar0) * (NIN_ * K_) + m0];
            ax0 = x[(row0 + ar0) * NIN_ + m0 / K_];
            const int n1 = tid + TPB;
            ar1 = n1 / (NIN_ * K_); const int m1 = n1 - ar1 * (NIN_ * K_);
            aj1 = iidx[(row0 + ar1) * (NIN_ * K_) + m1];
            ax1 = x[(row0 + ar1) * NIN_ + m1 / K_];
            const int n2 = tid + 2 * TPB;
            const int n2c = n2 < RPB * NIN_ * K_ ? n2 : 0;
            ar2 = n2c / (NIN_ * K_); const int m2 = n2c - ar2 * (NIN_ * K_);
            aj2 = iidx[(row0 + ar2) * (NIN_ * K_) + m2];
            ax2 = x[(row0 + ar2) * NIN_ + m2 / K_];
            if (n2 >= RPB * NIN_ * K_) aj2 = NIN_;
        }

        // ---- W0 in FULL f32 (64 VGPRs) ----
        const float* wb = W0 + (g * 4) * NIN_;
        float2 wA[4][4], wB[4][4];
        #pragma unroll
        for (int jj = 0; jj < 4; ++jj) {
            const int j  = q * 4 + jj * 32;
            const int j2 = (j + 2 > NIN_ - 2) ? (NIN_ - 2) : (j + 2);
            #pragma unroll
            for (int oo = 0; oo < 4; ++oo) {
                wA[jj][oo] = *reinterpret_cast<const float2*>(wb + oo * NIN_ + j);
                wB[jj][oo] = *reinterpret_cast<const float2*>(wb + oo * NIN_ + j2);
            }
        }

        int ej0, ej1, ej2;
        {
            const int t = tid < RPB * NOUT_ ? tid : 0;
            const int r = t / NOUT_, o = t - r * NOUT_;
            const int base = (row0 + r) * (NOUT_ * K_) + o * K_;
            ej0 = oidx[base]; ej1 = oidx[base + 1]; ej2 = oidx[base + 2];
        }
        const float4 b0v = *reinterpret_cast<const float4*>(b0 + g * 4);
        const float4 b1v = *reinterpret_cast<const float4*>(b1 + g * 4);
        const int    gD  = (g < 63) ? g : 0;
        const float2 b2v = *reinterpret_cast<const float2*>(b2 + gD * 2);

        // ======== phase A ========
        (&xe[0][0])[tid] = 0.0f;
        barrier_lds();
        if (aj0 < NIN_) atomicAdd(&xe[ar0][aj0], ax0);
        if (aj1 < NIN_) atomicAdd(&xe[ar1][aj1], ax1);
        if (aj2 < NIN_) atomicAdd(&xe[ar2][aj2], ax2);

        const float* wcp = W1 + (g * 4) * H1_ + q * 4;
        float4 wc1[4][4];
        #pragma unroll
        for (int jj = 0; jj < 4; ++jj)
            #pragma unroll
            for (int oo = 0; oo < 4; ++oo)
                wc1[jj][oo] = *reinterpret_cast<const float4*>(wcp + oo * H1_ + jj * 32);
        barrier_lds();

        // ======== phase B ========
        float4 wc2[4][4];
        {
            float acc[4][4] = {};
            #pragma unroll
            for (int jj = 0; jj < 2; ++jj) {
                const int j = q * 4 + jj * 32;
                float4 a[RPB];
                #pragma unroll
                for (int r = 0; r < RPB; ++r)
                    a[r] = *reinterpret_cast<const float4*>(&xe[r][j]);
                #pragma unroll
                for (int oo = 0; oo < 4; ++oo)
                    #pragma unroll
                    for (int r = 0; r < RPB; ++r) {
                        acc[oo][r] = fmaf(wA[jj][oo].x, a[r].x, acc[oo][r]);
                        acc[oo][r] = fmaf(wA[jj][oo].y, a[r].y, acc[oo][r]);
                        acc[oo][r] = fmaf(wB[jj][oo].x, a[r].z, acc[oo][r]);
                        acc[oo][r] = fmaf(wB[jj][oo].y, a[r].w, acc[oo][r]);
                    }
            }
            #pragma unroll
            for (int jj = 0; jj < 4; ++jj)
                #pragma unroll
                for (int oo = 0; oo < 4; ++oo)
                    wc2[jj][oo] = *reinterpret_cast<const float4*>(wcp + oo * H1_ + (jj + 4) * 32);
            #pragma unroll
            for (int jj = 2; jj < 4; ++jj) {
                const int j = q * 4 + jj * 32;
                float4 a[RPB];
                #pragma unroll
                for (int r = 0; r < RPB; ++r)
                    a[r] = *reinterpret_cast<const float4*>(&xe[r][j]);
                #pragma unroll
                for (int oo = 0; oo < 4; ++oo)
                    #pragma unroll
                    for (int r = 0; r < RPB; ++r) {
                        acc[oo][r] = fmaf(wA[jj][oo].x, a[r].x, acc[oo][r]);
                        acc[oo][r] = fmaf(wA[jj][oo].y, a[r].y, acc[oo][r]);
                        acc[oo][r] = fmaf(wB[jj][oo].x, a[r].z, acc[oo][r]);
                        acc[oo][r] = fmaf(wB[jj][oo].y, a[r].w, acc[oo][r]);
                    }
            }
            #pragma unroll
            for (int oo = 0; oo < 4; ++oo)
                #pragma unroll
                for (int r = 0; r < RPB; ++r) acc[oo][r] = qsum8(acc[oo][r]);
            float v0 = acc[0][0], v1 = acc[0][1];
            #pragma unroll
            for (int i = 1; i < 8; ++i) {
                v0 = (q == i) ? acc[(2 * i) >> 2][(2 * i) & 3]         : v0;
                v1 = (q == i) ? acc[(2 * i + 1) >> 2][(2 * i + 1) & 3] : v1;
            }
            const int oo = q >> 1, r0 = (q & 1) * 2;
            const float bias = (oo == 0) ? b0v.x : (oo == 1) ? b0v.y : (oo == 2) ? b0v.z : b0v.w;
            const int o = g * 4 + oo;
            h1s[r0][o]     = elu1(v0 + bias);
            h1s[r0 + 1][o] = elu1(v1 + bias);
        }
        barrier_lds();

        // ======== phase C ========
        const float* wdp = W2 + (gD * 2) * H2_ + q * 4;
        float4 wd[8][2];
        {
            float acc[4][4] = {};
            #pragma unroll
            for (int jj = 0; jj < 6; ++jj) {
                const float4* wrow = (jj < 4) ? wc1[jj] : wc2[jj - 4];
                const int j = q * 4 + jj * 32;
                float4 a[RPB];
                #pragma unroll
                for (int r = 0; r < RPB; ++r)
                    a[r] = *reinterpret_cast<const float4*>(&h1s[r][j]);
                #pragma unroll
                for (int oo = 0; oo < 4; ++oo)
                    #pragma unroll
                    for (int r = 0; r < RPB; ++r) {
                        acc[oo][r] = fmaf(wrow[oo].x, a[r].x, acc[oo][r]);
                        acc[oo][r] = fmaf(wrow[oo].y, a[r].y, acc[oo][r]);
                        acc[oo][r] = fmaf(wrow[oo].z, a[r].z, acc[oo][r]);
                        acc[oo][r] = fmaf(wrow[oo].w, a[r].w, acc[oo][r]);
                    }
            }
            #pragma unroll
            for (int jj = 0; jj < 8; ++jj)
                #pragma unroll
                for (int oo = 0; oo < 2; ++oo)
                    wd[jj][oo] = *reinterpret_cast<const float4*>(wdp + oo * H2_ + jj * 32);
            #pragma unroll
            for (int jj = 6; jj < 8; ++jj) {
                const float4* wrow = wc2[jj - 4];
                const int j = q * 4 + jj * 32;
                float4 a[RPB];
                #pragma unroll
                for (int r = 0; r < RPB; ++r)
                    a[r] = *reinterpret_cast<const float4*>(&h1s[r][j]);
                #pragma unroll
                for (int oo = 0; oo < 4; ++oo)
                    #pragma unroll
                    for (int r = 0; r < RPB; ++r) {
                        acc[oo][r] = fmaf(wrow[oo].x, a[r].x, acc[oo][r]);
                        acc[oo][r] = fmaf(wrow[oo].y, a[r].y, acc[oo][r]);
                        acc[oo][r] = fmaf(wrow[oo].z, a[r].z, acc[oo][r]);
                        acc[oo][r] = fmaf(wrow[oo].w, a[r].w, acc[oo][r]);
                    }
            }
            #pragma unroll
            for (int oo = 0; oo < 4; ++oo)
                #pragma unroll
                for (int r = 0; r < RPB; ++r) acc[oo][r] = qsum8(acc[oo][r]);
            float v0 = acc[0][0], v1 = acc[0][1];
            #pragma unroll
            for (int i = 1; i < 8; ++i) {
                v0 = (q == i) ? acc[(2 * i) >> 2][(2 * i) & 3]         : v0;
                v1 = (q == i) ? acc[(2 * i + 1) >> 2][(2 * i + 1) & 3] : v1;
            }
            const int oo = q >> 1, r0 = (q & 1) * 2;
            const float bias = (oo == 0) ? b1v.x : (oo == 1) ? b1v.y : (oo == 2) ? b1v.z : b1v.w;
            const int o = g * 4 + oo;
            h2s[r0][o]     = elu1(v0 + bias);
            h2s[r0 + 1][o] = elu1(v1 + bias);
        }
        barrier_lds();

        // ======== phase D ========
        {
            float acc[2][4] = {};
            #pragma unroll
            for (int jj = 0; jj < 8; ++jj) {
                const int j = q * 4 + jj * 32;
                float4 a[RPB];
                #pragma unroll
                for (int r = 0; r < RPB; ++r)
                    a[r] = *reinterpret_cast<const float4*>(&h2s[r][j]);
                #pragma unroll
                for (int oo = 0; oo < 2; ++oo)
                    #pragma unroll
                    for (int r = 0; r < RPB; ++r) {
                        acc[oo][r] = fmaf(wd[jj][oo].x, a[r].x, acc[oo][r]);
                        acc[oo][r] = fmaf(wd[jj][oo].y, a[r].y, acc[oo][r]);
                        acc[oo][r] = fmaf(wd[jj][oo].z, a[r].z, acc[oo][r]);
                        acc[oo][r] = fmaf(wd[jj][oo].w, a[r].w, acc[oo][r]);
                    }
            }
            #pragma unroll
            for (int oo = 0; oo < 2; ++oo)
                #pragma unroll
                for (int r = 0; r < RPB; ++r) acc[oo][r] = qsum8(acc[oo][r]);
            float v = acc[0][0];
            #pragma unroll
            for (int i = 1; i < 8; ++i) v = (q == i) ? acc[i >> 2][i & 3] : v;
            const int oo = q >> 2, rr = q & 3;
            if (g < 63) ts[rr][g * 2 + oo] = v + (oo ? b2v.y : b2v.x);
            else        ts[rr][126 + oo]   = 0.0f;
        }
        barrier_lds();

        // ======== phase E ========
        if (tid < RPB * NOUT_) {
            const int r = tid / NOUT_, o = tid - r * NOUT_;
            out[(row0 + r) * NOUT_ + o] = ts[r][ej0] + ts[r][ej1] + ts[r][ej2];
        }
        barrier_lds();   // isolate iterations (no cross-iter LDS races)
    }
}

extern "C" void kernel_launch(void* const* d_in, const int* in_sizes, int n_in,
                              void* d_out, int out_size, void* d_ws, size_t ws_size,
                              hipStream_t stream) {
    const float* x   = (const float*)d_in[0];
    const float* W0  = (const float*)d_in[1];
    const float* b0  = (const float*)d_in[2];
    const float* W1  = (const float*)d_in[3];
    const float* b1  = (const float*)d_in[4];
    const float* W2  = (const float*)d_in[5];
    const float* b2  = (const float*)d_in[6];
    const int*  iidx = (const int*)d_in[7];
    const int*  oidx = (const int*)d_in[8];
    float* out = (float*)d_out;

    bim_fused<<<B_ / RPB, TPB, 0, stream>>>(x, W0, b0, W1, b1, W2, b2, iidx, oidx, out);
}

// Round 15
// 15.800 us; speedup vs baseline: 3.7524x; 3.7524x over previous
//
#include <hip/hip_runtime.h>

#define B_    1024
#define NIN_  126
#define NOUT_ 126
#define K_    3
#define H1_   256
#define H2_   256
#define RPB   4
#define TPB   512    // 8 waves, 1 block/CU, grid = 256

__device__ __forceinline__ float elu1(float v) { return v > 0.0f ? v : expm1f(v); }

template<int CTRL>
__device__ __forceinline__ float dpp_add(float v) {
    int s = __builtin_amdgcn_update_dpp(0, __float_as_int(v), CTRL, 0xF, 0xF, true);
    return v + __int_as_float(s);
}
// sum over 8 consecutive lanes: xor1,xor2 via DPP, xor4 via ds_swizzle
__device__ __forceinline__ float qsum8(float v) {
    v = dpp_add<0xB1>(v);
    v = dpp_add<0x4E>(v);
    int s = __builtin_amdgcn_ds_swizzle(__float_as_int(v), 0x101F);
    return v + __int_as_float(s);
}
// barrier draining only LDS ops; global loads stay in flight
__device__ __forceinline__ void barrier_lds() {
    asm volatile("s_waitcnt lgkmcnt(0)\n\ts_barrier" ::: "memory");
}
// pin: nothing (incl. the loads above) may be scheduled across this point
__device__ __forceinline__ void pin() { __builtin_amdgcn_sched_barrier(0); }

__global__ __launch_bounds__(TPB, 1) void bim_fused(
    const float* __restrict__ x,  const float* __restrict__ W0,
    const float* __restrict__ b0, const float* __restrict__ W1,
    const float* __restrict__ b1, const float* __restrict__ W2,
    const float* __restrict__ b2, const int*  __restrict__ iidx,
    const int*  __restrict__ oidx, float* __restrict__ out)
{
    __shared__ float xe [RPB][128];
    __shared__ float h1s[RPB][H1_];
    __shared__ float h2s[RPB][H2_];
    __shared__ float ts [RPB][128];

    const int tid  = threadIdx.x;
    const int row0 = blockIdx.x * RPB;
    const int q    = tid & 7;
    const int g    = tid >> 3;

    // ---- phase-A operands ----
    int aj0, aj1, aj2, ar0, ar1, ar2; float ax0, ax1, ax2;
    {
        const int n0 = tid;
        ar0 = n0 / (NIN_ * K_); const int m0 = n0 - ar0 * (NIN_ * K_);
        aj0 = iidx[(row0 + ar0) * (NIN_ * K_) + m0];
        ax0 = x[(row0 + ar0) * NIN_ + m0 / K_];
        const int n1 = tid + TPB;
        ar1 = n1 / (NIN_ * K_); const int m1 = n1 - ar1 * (NIN_ * K_);
        aj1 = iidx[(row0 + ar1) * (NIN_ * K_) + m1];
        ax1 = x[(row0 + ar1) * NIN_ + m1 / K_];
        const int n2 = tid + 2 * TPB;
        const int n2c = n2 < RPB * NIN_ * K_ ? n2 : 0;
        ar2 = n2c / (NIN_ * K_); const int m2 = n2c - ar2 * (NIN_ * K_);
        aj2 = iidx[(row0 + ar2) * (NIN_ * K_) + m2];
        ax2 = x[(row0 + ar2) * NIN_ + m2 / K_];
        if (n2 >= RPB * NIN_ * K_) aj2 = NIN_;
    }

    // ---- W0 in FULL f32 (64 VGPRs); pinned so it cannot sink ----
    const float* wb = W0 + (g * 4) * NIN_;
    float2 wA[4][4], wB[4][4];
    #pragma unroll
    for (int jj = 0; jj < 4; ++jj) {
        const int j  = q * 4 + jj * 32;
        const int j2 = (j + 2 > NIN_ - 2) ? (NIN_ - 2) : (j + 2);
        #pragma unroll
        for (int oo = 0; oo < 4; ++oo) {
            wA[jj][oo] = *reinterpret_cast<const float2*>(wb + oo * NIN_ + j);
            wB[jj][oo] = *reinterpret_cast<const float2*>(wb + oo * NIN_ + j2);
        }
    }
    pin();   // W0 loads issued HERE, before phase A

    int ej0, ej1, ej2;
    {
        const int t = tid < RPB * NOUT_ ? tid : 0;
        const int r = t / NOUT_, o = t - r * NOUT_;
        const int base = (row0 + r) * (NOUT_ * K_) + o * K_;
        ej0 = oidx[base]; ej1 = oidx[base + 1]; ej2 = oidx[base + 2];
    }
    const float4 b0v = *reinterpret_cast<const float4*>(b0 + g * 4);
    const float4 b1v = *reinterpret_cast<const float4*>(b1 + g * 4);
    const int    gD  = (g < 63) ? g : 0;
    const float2 b2v = *reinterpret_cast<const float2*>(b2 + gD * 2);

    // ======== phase A: zero xe, barrier, scatter ========
    (&xe[0][0])[tid] = 0.0f;
    barrier_lds();
    if (aj0 < NIN_) atomicAdd(&xe[ar0][aj0], ax0);
    if (aj1 < NIN_) atomicAdd(&xe[ar1][aj1], ax1);
    if (aj2 < NIN_) atomicAdd(&xe[ar2][aj2], ax2);

    // ---- W1 first half (64 VGPRs), issued before the barrier; pinned ----
    const float* wcp = W1 + (g * 4) * H1_ + q * 4;
    float4 wc1[4][4];
    #pragma unroll
    for (int jj = 0; jj < 4; ++jj)
        #pragma unroll
        for (int oo = 0; oo < 4; ++oo)
            wc1[jj][oo] = *reinterpret_cast<const float4*>(wcp + oo * H1_ + jj * 32);
    pin();   // wc1 issued HERE, latency covered by phase B
    barrier_lds();

    // ======== phase B: h1 = elu(xe @ W0^T + b0) ========
    float4 wc2[4][4];
    {
        float acc[4][4] = {};
        #pragma unroll
        for (int jj = 0; jj < 2; ++jj) {
            const int j = q * 4 + jj * 32;
            float4 a[RPB];
            #pragma unroll
            for (int r = 0; r < RPB; ++r)
                a[r] = *reinterpret_cast<const float4*>(&xe[r][j]);
            #pragma unroll
            for (int oo = 0; oo < 4; ++oo)
                #pragma unroll
                for (int r = 0; r < RPB; ++r) {
                    acc[oo][r] = fmaf(wA[jj][oo].x, a[r].x, acc[oo][r]);
                    acc[oo][r] = fmaf(wA[jj][oo].y, a[r].y, acc[oo][r]);
                    acc[oo][r] = fmaf(wB[jj][oo].x, a[r].z, acc[oo][r]);
                    acc[oo][r] = fmaf(wB[jj][oo].y, a[r].w, acc[oo][r]);
                }
        }
        // ---- W1 second half (64 VGPRs), issued mid-phase; pinned ----
        #pragma unroll
        for (int jj = 0; jj < 4; ++jj)
            #pragma unroll
            for (int oo = 0; oo < 4; ++oo)
                wc2[jj][oo] = *reinterpret_cast<const float4*>(wcp + oo * H1_ + (jj + 4) * 32);
        pin();
        #pragma unroll
        for (int jj = 2; jj < 4; ++jj) {
            const int j = q * 4 + jj * 32;
            float4 a[RPB];
            #pragma unroll
            for (int r = 0; r < RPB; ++r)
                a[r] = *reinterpret_cast<const float4*>(&xe[r][j]);
            #pragma unroll
            for (int oo = 0; oo < 4; ++oo)
                #pragma unroll
                for (int r = 0; r < RPB; ++r) {
                    acc[oo][r] = fmaf(wA[jj][oo].x, a[r].x, acc[oo][r]);
                    acc[oo][r] = fmaf(wA[jj][oo].y, a[r].y, acc[oo][r]);
                    acc[oo][r] = fmaf(wB[jj][oo].x, a[r].z, acc[oo][r]);
                    acc[oo][r] = fmaf(wB[jj][oo].y, a[r].w, acc[oo][r]);
                }
        }
        #pragma unroll
        for (int oo = 0; oo < 4; ++oo)
            #pragma unroll
            for (int r = 0; r < RPB; ++r) acc[oo][r] = qsum8(acc[oo][r]);
        float v0 = acc[0][0], v1 = acc[0][1];
        #pragma unroll
        for (int i = 1; i < 8; ++i) {
            v0 = (q == i) ? acc[(2 * i) >> 2][(2 * i) & 3]         : v0;
            v1 = (q == i) ? acc[(2 * i + 1) >> 2][(2 * i + 1) & 3] : v1;
        }
        const int oo = q >> 1, r0 = (q & 1) * 2;
        const float bias = (oo == 0) ? b0v.x : (oo == 1) ? b0v.y : (oo == 2) ? b0v.z : b0v.w;
        const int o = g * 4 + oo;
        h1s[r0][o]     = elu1(v0 + bias);
        h1s[r0 + 1][o] = elu1(v1 + bias);
    }
    barrier_lds();

    // ======== phase C: h2 = elu(h1 @ W1^T + b1) ========
    const float* wdp = W2 + (gD * 2) * H2_ + q * 4;
    float4 wd[8][2];
    {
        float acc[4][4] = {};
        #pragma unroll
        for (int jj = 0; jj < 6; ++jj) {
            const float4* wrow = (jj < 4) ? wc1[jj] : wc2[jj - 4];
            const int j = q * 4 + jj * 32;
            float4 a[RPB];
            #pragma unroll
            for (int r = 0; r < RPB; ++r)
                a[r] = *reinterpret_cast<const float4*>(&h1s[r][j]);
            #pragma unroll
            for (int oo = 0; oo < 4; ++oo)
                #pragma unroll
                for (int r = 0; r < RPB; ++r) {
                    acc[oo][r] = fmaf(wrow[oo].x, a[r].x, acc[oo][r]);
                    acc[oo][r] = fmaf(wrow[oo].y, a[r].y, acc[oo][r]);
                    acc[oo][r] = fmaf(wrow[oo].z, a[r].z, acc[oo][r]);
                    acc[oo][r] = fmaf(wrow[oo].w, a[r].w, acc[oo][r]);
                }
        }
        // ---- W2 in FULL f32 (64 VGPRs), issued mid-phase; pinned ----
        #pragma unroll
        for (int jj = 0; jj < 8; ++jj)
            #pragma unroll
            for (int oo = 0; oo < 2; ++oo)
                wd[jj][oo] = *reinterpret_cast<const float4*>(wdp + oo * H2_ + jj * 32);
        pin();
        #pragma unroll
        for (int jj = 6; jj < 8; ++jj) {
            const float4* wrow = wc2[jj - 4];
            const int j = q * 4 + jj * 32;
            float4 a[RPB];
            #pragma unroll
            for (int r = 0; r < RPB; ++r)
                a[r] = *reinterpret_cast<const float4*>(&h1s[r][j]);
            #pragma unroll
            for (int oo = 0; oo < 4; ++oo)
                #pragma unroll
                for (int r = 0; r < RPB; ++r) {
                    acc[oo][r] = fmaf(wrow[oo].x, a[r].x, acc[oo][r]);
                    acc[oo][r] = fmaf(wrow[oo].y, a[r].y, acc[oo][r]);
                    acc[oo][r] = fmaf(wrow[oo].z, a[r].z, acc[oo][r]);
                    acc[oo][r] = fmaf(wrow[oo].w, a[r].w, acc[oo][r]);
                }
        }
        #pragma unroll
        for (int oo = 0; oo < 4; ++oo)
            #pragma unroll
            for (int r = 0; r < RPB; ++r) acc[oo][r] = qsum8(acc[oo][r]);
        float v0 = acc[0][0], v1 = acc[0][1];
        #pragma unroll
        for (int i = 1; i < 8; ++i) {
            v0 = (q == i) ? acc[(2 * i) >> 2][(2 * i) & 3]         : v0;
            v1 = (q == i) ? acc[(2 * i + 1) >> 2][(2 * i + 1) & 3] : v1;
        }
        const int oo = q >> 1, r0 = (q & 1) * 2;
        const float bias = (oo == 0) ? b1v.x : (oo == 1) ? b1v.y : (oo == 2) ? b1v.z : b1v.w;
        const int o = g * 4 + oo;
        h2s[r0][o]     = elu1(v0 + bias);
        h2s[r0 + 1][o] = elu1(v1 + bias);
    }
    barrier_lds();

    // ======== phase D: ts[r][j] = h2s[r].W2[j,:] + b2[j] ========
    {
        float acc[2][4] = {};
        #pragma unroll
        for (int jj = 0; jj < 8; ++jj) {
            const int j = q * 4 + jj * 32;
            float4 a[RPB];
            #pragma unroll
            for (int r = 0; r < RPB; ++r)
                a[r] = *reinterpret_cast<const float4*>(&h2s[r][j]);
            #pragma unroll
            for (int oo = 0; oo < 2; ++oo)
                #pragma unroll
                for (int r = 0; r < RPB; ++r) {
                    acc[oo][r] = fmaf(wd[jj][oo].x, a[r].x, acc[oo][r]);
                    acc[oo][r] = fmaf(wd[jj][oo].y, a[r].y, acc[oo][r]);
                    acc[oo][r] = fmaf(wd[jj][oo].z, a[r].z, acc[oo][r]);
                    acc[oo][r] = fmaf(wd[jj][oo].w, a[r].w, acc[oo][r]);
                }
        }
        #pragma unroll
        for (int oo = 0; oo < 2; ++oo)
            #pragma unroll
            for (int r = 0; r < RPB; ++r) acc[oo][r] = qsum8(acc[oo][r]);
        float v = acc[0][0];
        #pragma unroll
        for (int i = 1; i < 8; ++i) v = (q == i) ? acc[i >> 2][i & 3] : v;
        const int oo = q >> 2, rr = q & 3;
        if (g < 63) ts[rr][g * 2 + oo] = v + (oo ? b2v.y : b2v.x);
        else        ts[rr][126 + oo]   = 0.0f;
    }
    barrier_lds();

    // ======== phase E ========
    if (tid < RPB * NOUT_) {
        const int r = tid / NOUT_, o = tid - r * NOUT_;
        out[(row0 + r) * NOUT_ + o] = ts[r][ej0] + ts[r][ej1] + ts[r][ej2];
    }
}

extern "C" void kernel_launch(void* const* d_in, const int* in_sizes, int n_in,
                              void* d_out, int out_size, void* d_ws, size_t ws_size,
                              hipStream_t stream) {
    const float* x   = (const float*)d_in[0];
    const float* W0  = (const float*)d_in[1];
    const float* b0  = (const float*)d_in[2];
    const float* W1  = (const float*)d_in[3];
    const float* b1  = (const float*)d_in[4];
    const float* W2  = (const float*)d_in[5];
    const float* b2  = (const float*)d_in[6];
    const int*  iidx = (const int*)d_in[7];
    const int*  oidx = (const int*)d_in[8];
    float* out = (float*)d_out;

    bim_fused<<<B_ / RPB, TPB, 0, stream>>>(x, W0, b0, W1, b1, W2, b2, iidx, oidx, out);
}